// Round 3
// baseline (125.603 us; speedup 1.0000x reference)
//
#include <hip/hip_runtime.h>
#include <hip/hip_cooperative_groups.h>
#include <stdint.h>

namespace cg = cooperative_groups;

// SCLinear: out = sc_mat_mac_p(x, W, b, lut, 32)  (forward value of
// lin + stop_grad(p - lin) is exactly p).
// lut[i][j] == floor(i*j/32)  =>  sgn*lut[|a|,|b|] == trunc-toward-zero(a*b/32).
// Exact small-integer arithmetic; no lut memory needed.
//
// ONE cooperative dispatch (512 blocks x 256 threads, co-resident at 2 blk/CU):
//   phase 1: each thread reduces one float4 of {x,W,b}; block partials ->
//            512 disjoint slots in d_ws (no memset, no atomics).
//   grid.sync()
//   phase 2: every block reduces the 512 partial pairs (4 KB, L2-hot),
//            computes scales, quantizes its x-row into LDS and W inline,
//            integer MAC loop, writes out.

#define MROWS 512
#define KDIM  256
#define OCOLS 256

__device__ __forceinline__ void get_scales(float amax, float dmax, int& e2, int& e1) {
    if (amax == 0.0f) amax = 1.0f;
    if (dmax == 0.0f) dmax = 1.0f;
    float q2 = 32.0f / amax;
    float q1 = 32.0f / dmax;
    int f2 = (q2 >= 1073741824.0f) ? 0x40000000 : (int)floorf(q2);
    int f1 = (q1 >= 1073741824.0f) ? 0x40000000 : (int)floorf(q1);
    if (f2 < 1) f2 = 1;
    if (f1 < 1) f1 = 1;
    e2 = 31 - __clz(f2);
    e1 = 31 - __clz(f1);
}

__device__ __forceinline__ float max4(float4 v) {
    return fmaxf(fmaxf(fabsf(v.x), fabsf(v.y)), fmaxf(fabsf(v.z), fabsf(v.w)));
}

__global__ __launch_bounds__(256)
void k_fused(float* __restrict__ wsp, const float* __restrict__ x,
             const float* __restrict__ W, const float* __restrict__ b,
             float* __restrict__ out) {
    __shared__ unsigned int a_sh[KDIM / 4];
    __shared__ float sm[8];
    __shared__ float s_max[2];

    const int m = blockIdx.x;
    const int o = threadIdx.x;
    const int wave = o >> 6;

    // ---- phase 1: partial abs-max over one float4 per thread ----
    {
        const int g = m * 256 + o;                    // 0..131071
        float va = 0.0f, vd = 0.0f;
        if (g < 32768) {                              // x: 32768 float4
            va = max4(((const float4*)x)[g]);
        } else if (g < 49152) {                       // W: 16384 float4
            vd = max4(((const float4*)W)[g - 32768]);
        } else if (g < 49216) {                       // b: 64 float4
            vd = max4(((const float4*)b)[g - 49152]);
        }
        #pragma unroll
        for (int s = 32; s >= 1; s >>= 1) {
            va = fmaxf(va, __shfl_xor(va, s, 64));
            vd = fmaxf(vd, __shfl_xor(vd, s, 64));
        }
        if ((o & 63) == 0) { sm[2 * wave] = va; sm[2 * wave + 1] = vd; }
        __syncthreads();
        if (o == 0) {
            wsp[2 * m]     = fmaxf(fmaxf(sm[0], sm[2]), fmaxf(sm[4], sm[6]));
            wsp[2 * m + 1] = fmaxf(fmaxf(sm[1], sm[3]), fmaxf(sm[5], sm[7]));
        }
    }

    cg::this_grid().sync();

    // ---- phase 2a: reduce the 512 partial pairs (each block, redundantly) ----
    {
        float va = fmaxf(wsp[2 * o], wsp[2 * (o + 256)]);
        float vd = fmaxf(wsp[2 * o + 1], wsp[2 * (o + 256) + 1]);
        #pragma unroll
        for (int s = 32; s >= 1; s >>= 1) {
            va = fmaxf(va, __shfl_xor(va, s, 64));
            vd = fmaxf(vd, __shfl_xor(vd, s, 64));
        }
        if ((o & 63) == 0) { sm[2 * wave] = va; sm[2 * wave + 1] = vd; }
        __syncthreads();
        if (o == 0) {
            s_max[0] = fmaxf(fmaxf(sm[0], sm[2]), fmaxf(sm[4], sm[6]));
            s_max[1] = fmaxf(fmaxf(sm[1], sm[3]), fmaxf(sm[5], sm[7]));
        }
        __syncthreads();
    }

    int e2, e1;
    get_scales(s_max[0], s_max[1], e2, e1);
    const float sn2f = (float)(1 << e2);
    const float sn1f = (float)(1 << e1);

    // ---- phase 2b: quantize this block's x-row into LDS (packed int8) ----
    if (o < KDIM / 4) {
        float4 xv = ((const float4*)(x + (size_t)m * KDIM))[o];
        int a0 = (int)(xv.x * sn2f) & 0xFF;
        int a1 = (int)(xv.y * sn2f) & 0xFF;
        int a2 = (int)(xv.z * sn2f) & 0xFF;
        int a3 = (int)(xv.w * sn2f) & 0xFF;
        a_sh[o] = (unsigned int)(a0 | (a1 << 8) | (a2 << 16) | (a3 << 24));
    }
    __syncthreads();

    // ---- phase 2c: integer MAC over K with inline W quantization ----
    const float4* wrow = (const float4*)(W + (size_t)o * KDIM);
    int sum = 0;
    #pragma unroll 8
    for (int kk = 0; kk < KDIM / 4; ++kk) {
        float4 wv = wrow[kk];
        unsigned int ap = a_sh[kk];
        float wfv[4] = {wv.x, wv.y, wv.z, wv.w};
        #pragma unroll
        for (int j = 0; j < 4; ++j) {
            int bv = (int)(wfv[j] * sn1f);
            int av = ((int)(ap << (24 - 8 * j))) >> 24;   // sign-extended byte j
            int s  = av * bv;
            sum += (s + ((s >> 31) & 31)) >> 5;           // == sgn*lut[|av|,|bv|]
        }
    }

    int cc = (int)(b[o] * sn1f);
    int d  = ((sum + ((sum >> 31) & ((1 << e2) - 1))) >> e2) + cc;
    out[(size_t)m * OCOLS + o] = (float)d / sn1f;
}

extern "C" void kernel_launch(void* const* d_in, const int* in_sizes, int n_in,
                              void* d_out, int out_size, void* d_ws, size_t ws_size,
                              hipStream_t stream) {
    const float* x = (const float*)d_in[0];
    const float* W = (const float*)d_in[1];
    const float* b = (const float*)d_in[2];
    // d_in[3] (lut) unused: lut[i][j] == floor(i*j/32), computed in-ALU.
    float* out = (float*)d_out;
    float* wsp = (float*)d_ws;   // 1024 floats, fully overwritten in phase 1

    void* args[] = { (void*)&wsp, (void*)&x, (void*)&W, (void*)&b, (void*)&out };
    hipLaunchCooperativeKernel((const void*)k_fused, dim3(MROWS), dim3(256),
                               args, 0, stream);
}

// Round 4
// 86.251 us; speedup vs baseline: 1.4562x; 1.4562x over previous
//
#include <hip/hip_runtime.h>
#include <stdint.h>

// SCLinear: out = sc_mat_mac_p(x, W, b, lut, 32)  (forward value of
// lin + stop_grad(p - lin) is exactly p).
// lut[i][j] == floor(i*j/32)  =>  sgn*lut[|a|,|b|] == trunc-toward-zero(a*b/32).
// Exact small-integer arithmetic; no lut memory needed.
//
// ONE regular dispatch, hand-rolled device-atomic barrier (cg grid sync
// measured ~50us on this harness -- R3 post-mortem).
//   phase 1: each block reduces its 4KB slice of {x,W,b}; thread 0 publishes
//            the partial pair + a MAGIC flag via device-scope atomics.
//   block 0: polls all 512 flags, gathers partials, computes scale exponents,
//            publishes one tagged result word.
//   all blocks: spin on the result word, then quantize x-row to LDS,
//            integer MAC over K with inline W quantization, write out.
// All cross-block communication is via atomic RMWs (device-coherent point),
// so per-XCD L2 non-coherence cannot serve stale data. Poison-independent:
// only assumes d_ws poison != our MAGIC constants.
// Co-residency: 512 blocks, <=128 VGPR via __launch_bounds__(256,2)
// -> >=2 blocks/CU x 256 CUs = capacity >= 1024 >= 512.

#define MROWS 512
#define KDIM  256
#define OCOLS 256

#define MAGIC_FLAG 0x5C1B07A1u
#define MAGIC_TAG  0x51AB0000u

__device__ __forceinline__ void get_scales(float amax, float dmax, int& e2, int& e1) {
    if (amax == 0.0f) amax = 1.0f;
    if (dmax == 0.0f) dmax = 1.0f;
    float q2 = 32.0f / amax;
    float q1 = 32.0f / dmax;
    int f2 = (q2 >= 1073741824.0f) ? 0x40000000 : (int)floorf(q2);
    int f1 = (q1 >= 1073741824.0f) ? 0x40000000 : (int)floorf(q1);
    if (f2 < 1) f2 = 1;
    if (f1 < 1) f1 = 1;
    e2 = 31 - __clz(f2);
    e1 = 31 - __clz(f1);
}

__device__ __forceinline__ float max4(float4 v) {
    return fmaxf(fmaxf(fabsf(v.x), fabsf(v.y)), fmaxf(fabsf(v.z), fabsf(v.w)));
}

// wsp layout (uint):
//   [0]            tagged result word: MAGIC_TAG | (e2<<8) | e1
//   [64 + i]       arrival flag of block i (MAGIC_FLAG), i < 512
//   [1024 + 2i +k] partial amax/dmax bits of block i
__global__ __launch_bounds__(256, 2)
void k_one(unsigned int* __restrict__ wsp, const float* __restrict__ x,
           const float* __restrict__ W, const float* __restrict__ b,
           float* __restrict__ out) {
    __shared__ unsigned int a_sh[KDIM / 4];
    __shared__ float sm[8];
    __shared__ unsigned int s_res;

    const int m = blockIdx.x;
    const int o = threadIdx.x;
    const int wave = o >> 6;

    // ---- phase 1: block-local abs-max over one float4 per thread ----
    {
        const int g = m * 256 + o;                    // 0..131071
        float va = 0.0f, vd = 0.0f;
        if (g < 32768) {                              // x: 32768 float4
            va = max4(((const float4*)x)[g]);
        } else if (g < 49152) {                       // W: 16384 float4
            vd = max4(((const float4*)W)[g - 32768]);
        } else if (g < 49216) {                       // b: 64 float4
            vd = max4(((const float4*)b)[g - 49152]);
        }
        #pragma unroll
        for (int s = 32; s >= 1; s >>= 1) {
            va = fmaxf(va, __shfl_xor(va, s, 64));
            vd = fmaxf(vd, __shfl_xor(vd, s, 64));
        }
        if ((o & 63) == 0) { sm[2 * wave] = va; sm[2 * wave + 1] = vd; }
        __syncthreads();
        if (o == 0) {
            float a = fmaxf(fmaxf(sm[0], sm[2]), fmaxf(sm[4], sm[6]));
            float d = fmaxf(fmaxf(sm[1], sm[3]), fmaxf(sm[5], sm[7]));
            atomicExch(&wsp[1024 + 2 * m],     __float_as_uint(a));
            atomicExch(&wsp[1024 + 2 * m + 1], __float_as_uint(d));
            __threadfence();                           // partials before flag
            atomicExch(&wsp[64 + m], MAGIC_FLAG);
        }
    }

    // ---- block 0: gather all partials, publish scale exponents ----
    if (m == 0) {
        bool all;
        do {
            unsigned int f0 = atomicOr(&wsp[64 + o], 0u);
            unsigned int f1 = atomicOr(&wsp[64 + 256 + o], 0u);
            int ok = (f0 == MAGIC_FLAG) && (f1 == MAGIC_FLAG);
            all = (bool)__syncthreads_and(ok);
            if (!all) __builtin_amdgcn_s_sleep(2);
        } while (!all);
        __threadfence();
        float va = fmaxf(__uint_as_float(atomicOr(&wsp[1024 + 2 * o], 0u)),
                         __uint_as_float(atomicOr(&wsp[1024 + 2 * (o + 256)], 0u)));
        float vd = fmaxf(__uint_as_float(atomicOr(&wsp[1024 + 2 * o + 1], 0u)),
                         __uint_as_float(atomicOr(&wsp[1024 + 2 * (o + 256) + 1], 0u)));
        #pragma unroll
        for (int s = 32; s >= 1; s >>= 1) {
            va = fmaxf(va, __shfl_xor(va, s, 64));
            vd = fmaxf(vd, __shfl_xor(vd, s, 64));
        }
        if ((o & 63) == 0) { sm[2 * wave] = va; sm[2 * wave + 1] = vd; }
        __syncthreads();
        if (o == 0) {
            float a = fmaxf(fmaxf(sm[0], sm[2]), fmaxf(sm[4], sm[6]));
            float d = fmaxf(fmaxf(sm[1], sm[3]), fmaxf(sm[5], sm[7]));
            int e2, e1;
            get_scales(a, d, e2, e1);
            atomicExch(&wsp[0], MAGIC_TAG | ((unsigned)e2 << 8) | (unsigned)e1);
        }
    }

    // ---- all blocks: spin on the single result word ----
    if (o == 0) {
        unsigned int r;
        while ((((r = atomicOr(&wsp[0], 0u)) & 0xFFFF0000u) != MAGIC_TAG))
            __builtin_amdgcn_s_sleep(2);
        s_res = r;
    }
    __syncthreads();

    const int e2 = (int)((s_res >> 8) & 0xFFu);
    const int e1 = (int)(s_res & 0xFFu);
    const float sn2f = (float)(1 << e2);
    const float sn1f = (float)(1 << e1);

    // ---- quantize this block's x-row into LDS (packed int8) ----
    if (o < KDIM / 4) {
        float4 xv = ((const float4*)(x + (size_t)m * KDIM))[o];
        int a0 = (int)(xv.x * sn2f) & 0xFF;
        int a1 = (int)(xv.y * sn2f) & 0xFF;
        int a2 = (int)(xv.z * sn2f) & 0xFF;
        int a3 = (int)(xv.w * sn2f) & 0xFF;
        a_sh[o] = (unsigned int)(a0 | (a1 << 8) | (a2 << 16) | (a3 << 24));
    }
    __syncthreads();

    // ---- integer MAC over K with inline W quantization ----
    const float4* wrow = (const float4*)(W + (size_t)o * KDIM);
    int sum = 0;
    #pragma unroll 8
    for (int kk = 0; kk < KDIM / 4; ++kk) {
        float4 wv = wrow[kk];
        unsigned int ap = a_sh[kk];
        float wfv[4] = {wv.x, wv.y, wv.z, wv.w};
        #pragma unroll
        for (int j = 0; j < 4; ++j) {
            int bv = (int)(wfv[j] * sn1f);
            int av = ((int)(ap << (24 - 8 * j))) >> 24;   // sign-extended byte j
            int s  = av * bv;
            sum += (s + ((s >> 31) & 31)) >> 5;           // == sgn*lut[|av|,|bv|]
        }
    }

    int cc = (int)(b[o] * sn1f);
    int d  = ((sum + ((sum >> 31) & ((1 << e2) - 1))) >> e2) + cc;
    out[(size_t)m * OCOLS + o] = (float)d / sn1f;
}

extern "C" void kernel_launch(void* const* d_in, const int* in_sizes, int n_in,
                              void* d_out, int out_size, void* d_ws, size_t ws_size,
                              hipStream_t stream) {
    const float* x = (const float*)d_in[0];
    const float* W = (const float*)d_in[1];
    const float* b = (const float*)d_in[2];
    // d_in[3] (lut) unused: lut[i][j] == floor(i*j/32), computed in-ALU.
    float* out = (float*)d_out;
    unsigned int* wsp = (unsigned int*)d_ws;   // 8 KB used; every word we read
                                               // is first written by us or
                                               // validated against MAGIC tags.

    k_one<<<MROWS, 256, 0, stream>>>(wsp, x, W, b, out);
}